// Round 6
// baseline (135.253 us; speedup 1.0000x reference)
//
#include <hip/hip_runtime.h>

#define L_TOTAL   32768
#define E_DIM     64
#define K_TOTAL   1024
#define NT_TOTAL  64                  // K_TOTAL / 16
#define OUT_STRIDE 2097152            // L_TOTAL * E_DIM
#define XPAD      68                  // fp32 x-tile LDS pitch (words)

// staging record: per nt = 1280 words (5120 B):
//   [0,256)   kt0 hi frags   (64 lanes x 16 B)
//   [256,512) kt1 hi
//   [512,768) kt0 lo
//   [768,1024) kt1 lo
//   [1024,1088) norms (64 f32, dup x4 over quads)
//   [1088,1280) pad (never read)
#define NT_WORDS  1280
#define CHUNK_NT  4
#define CHUNK_WORDS (CHUNK_NT * NT_WORDS)   // 5120 words = 20480 B

typedef _Float16 half_t;
typedef _Float16 half8  __attribute__((ext_vector_type(8)));
typedef float    floatx4 __attribute__((ext_vector_type(4)));

// ---------------------------------------------------------------------------
// Codebook fp32 -> staged records (f16 hi/lo fragments + norms).
// Grid 64 x 128 thr: kt = t>>6, lane = t&63.
// Fragment (nt,kt,lane) = e[nt*16 + (lane&15)][kt*32 + (lane>>4)*8 .. +8].
// ---------------------------------------------------------------------------
__global__ __launch_bounds__(128)
void vq_swizzle_kernel(const float* __restrict__ emb, float* __restrict__ ebuf) {
    __shared__ float s_p[128];
    __shared__ float s_n[16];
    const int nt   = blockIdx.x;
    const int t    = threadIdx.x;
    const int kt   = t >> 6;
    const int lane = t & 63;
    const int q    = lane >> 4;
    const int ln   = lane & 15;

    const float* src = emb + (size_t)(nt * 16 + ln) * E_DIM + kt * 32 + q * 8;
    float4 v0 = *(const float4*)src;
    float4 v1 = *(const float4*)(src + 4);
    float f[8] = {v0.x, v0.y, v0.z, v0.w, v1.x, v1.y, v1.z, v1.w};

    half8 h, l;
    float s = 0.f;
    #pragma unroll
    for (int j = 0; j < 8; ++j) {
        half_t hh = (half_t)f[j];
        half_t ll = (half_t)(f[j] - (float)hh);
        h[j] = hh;
        l[j] = ll;
        s = fmaf(f[j], f[j], s);
    }
    float* rec = ebuf + (size_t)nt * NT_WORDS;
    *(half8*)(rec + kt * 256 + lane * 4)       = h;   // hi
    *(half8*)(rec + 512 + kt * 256 + lane * 4) = l;   // lo

    s_p[t] = s;
    __syncthreads();
    if (t < 16) {
        float n = 0.f;
        #pragma unroll
        for (int u = 0; u < 8; ++u)
            n += s_p[(u >> 2) * 64 + (u & 3) * 16 + t];
        s_n[t] = n;
    }
    __syncthreads();
    if (t < 64) rec[1024 + t] = s_n[t & 15];
}

// ---------------------------------------------------------------------------
// Fused distances + argmin + epilogue, LDS-sourced B.
// Block = 4 waves, M = 128 latents (wave owns 32, scans ALL K). Grid = 256
// (1 block/CU). B staged to LDS in 4-nt chunks through a register double
// buffer (prefetch overlaps compute); per-block rotated chunk order breaks
// the cross-CU lockstep on the hot codebook. Argmin is lexicographic
// (dist, index) == first-occurrence, order-independent.
// ---------------------------------------------------------------------------
__global__ __launch_bounds__(256, 1)
void vq_fused_kernel(const float* __restrict__ x,
                     const float* __restrict__ emb,
                     const float* __restrict__ ebuf,
                     float* __restrict__ out) {
    __shared__ float s_x[128 * XPAD];     // 34816 B fp32 x tile
    __shared__ float s_b[CHUNK_WORDS];    // 20480 B staged B chunk
    __shared__ int   s_fin[128];

    const int tid   = threadIdx.x;
    const int wave  = tid >> 6;
    const int lane  = tid & 63;
    const int q     = lane >> 4;
    const int ln    = lane & 15;
    const int mbase = blockIdx.x * 128;
    const int rot   = ((blockIdx.x >> 3) + blockIdx.x) & 15;

    // ---- stage x tile: coalesced float4 -> padded LDS (8 per thread)
    {
        const float4* xg = (const float4*)(x + (size_t)mbase * E_DIM);
        #pragma unroll
        for (int i = 0; i < 8; ++i) {
            const int f   = i * 256 + tid;
            const int row = f >> 4;
            const int col = (f & 15) * 4;
            *(float4*)(&s_x[row * XPAD + col]) = xg[f];
        }
    }
    __syncthreads();

    // ---- A fragments (hi/lo) + row norms for this wave's 32 latents
    half8 A[2][2][2];                  // [rt][kt][hi/lo]
    float nrm[2];
    #pragma unroll
    for (int rt = 0; rt < 2; ++rt) {
        const float* xr = &s_x[(wave * 32 + rt * 16 + ln) * XPAD + q * 8];
        float s = 0.f;
        #pragma unroll
        for (int kt = 0; kt < 2; ++kt) {
            float4 v0 = *(const float4*)(xr + kt * 32);
            float4 v1 = *(const float4*)(xr + kt * 32 + 4);
            float f[8] = {v0.x, v0.y, v0.z, v0.w, v1.x, v1.y, v1.z, v1.w};
            #pragma unroll
            for (int j = 0; j < 8; ++j) {
                half_t hh = (half_t)f[j];
                half_t ll = (half_t)(f[j] - (float)hh);
                A[rt][kt][0][j] = hh;
                A[rt][kt][1][j] = ll;
                s = fmaf(f[j], f[j], s);
            }
        }
        s += __shfl_xor(s, 16, 64);
        s += __shfl_xor(s, 32, 64);
        nrm[rt] = s;
    }
    floatx4 xq[2];
    #pragma unroll
    for (int rt = 0; rt < 2; ++rt)
        #pragma unroll
        for (int r = 0; r < 4; ++r)
            xq[rt][r] = __shfl(nrm[rt], q * 4 + r, 64);

    float best[2][4];
    int   bidx[2][4];
    #pragma unroll
    for (int rt = 0; rt < 2; ++rt)
        #pragma unroll
        for (int r = 0; r < 4; ++r) { best[rt][r] = 3.402823466e+38f; bidx[rt][r] = 0x7fffffff; }

    // ---- prefetch first chunk into registers (5 float4 / thread = 20 KB)
    float4 rb[5];
    {
        const float4* cp = (const float4*)ebuf + (size_t)rot * (CHUNK_WORDS / 4);
        #pragma unroll
        for (int i = 0; i < 5; ++i) rb[i] = cp[i * 256 + tid];
    }

    #pragma unroll 1
    for (int c = 0; c < 16; ++c) {
        const int phys = (c + rot) & 15;          // chunk of nt = phys*4 .. +4
        __syncthreads();                           // prev chunk fully consumed
        #pragma unroll
        for (int i = 0; i < 5; ++i)
            ((float4*)s_b)[i * 256 + tid] = rb[i];
        __syncthreads();                           // chunk visible to all

        if (c < 15) {                              // prefetch next (overlaps compute)
            const int pn = (c + 1 + rot) & 15;
            const float4* cp = (const float4*)ebuf + (size_t)pn * (CHUNK_WORDS / 4);
            #pragma unroll
            for (int i = 0; i < 5; ++i) rb[i] = cp[i * 256 + tid];
        }

        #pragma unroll
        for (int ntl = 0; ntl < CHUNK_NT; ++ntl) {
            const float* rec = &s_b[ntl * NT_WORDS];
            const half8 bh0 = *(const half8*)(rec + lane * 4);
            const half8 bh1 = *(const half8*)(rec + 256 + lane * 4);
            const half8 bl0 = *(const half8*)(rec + 512 + lane * 4);
            const half8 bl1 = *(const half8*)(rec + 768 + lane * 4);
            const float env = rec[1024 + lane];
            const int   nt  = phys * CHUNK_NT + ntl;
            const int   kg  = nt * 16 + ln;

            #pragma unroll
            for (int rt = 0; rt < 2; ++rt) {
                floatx4 Ca = {0.f, 0.f, 0.f, 0.f};
                floatx4 Cb = {0.f, 0.f, 0.f, 0.f};
                Ca = __builtin_amdgcn_mfma_f32_16x16x32_f16(A[rt][0][0], bh0, Ca, 0, 0, 0);
                Ca = __builtin_amdgcn_mfma_f32_16x16x32_f16(A[rt][1][0], bh1, Ca, 0, 0, 0);
                Cb = __builtin_amdgcn_mfma_f32_16x16x32_f16(A[rt][0][1], bh0, Cb, 0, 0, 0);
                Cb = __builtin_amdgcn_mfma_f32_16x16x32_f16(A[rt][1][1], bh1, Cb, 0, 0, 0);
                Cb = __builtin_amdgcn_mfma_f32_16x16x32_f16(A[rt][0][0], bl0, Cb, 0, 0, 0);
                Cb = __builtin_amdgcn_mfma_f32_16x16x32_f16(A[rt][1][0], bl1, Cb, 0, 0, 0);
                #pragma unroll
                for (int r = 0; r < 4; ++r) {
                    float dot = Ca[r] + Cb[r];
                    // reference op order: (xx - 2*dot) + en, no FMA contraction
                    float d = __fadd_rn(__fsub_rn(xq[rt][r], __fmul_rn(2.0f, dot)), env);
                    if (d < best[rt][r] || (d == best[rt][r] && kg < bidx[rt][r])) {
                        best[rt][r] = d; bidx[rt][r] = kg;
                    }
                }
            }
        }
    }

    // ---- argmin across the 16 col-lanes of each quad (ties -> lower index)
    #pragma unroll
    for (int o = 1; o < 16; o <<= 1) {
        #pragma unroll
        for (int rt = 0; rt < 2; ++rt)
            #pragma unroll
            for (int r = 0; r < 4; ++r) {
                float ob = __shfl_xor(best[rt][r], o, 64);
                int   oi = __shfl_xor(bidx[rt][r], o, 64);
                if (ob < best[rt][r] || (ob == best[rt][r] && oi < bidx[rt][r])) {
                    best[rt][r] = ob; bidx[rt][r] = oi;
                }
            }
    }
    if (ln == 0) {
        #pragma unroll
        for (int rt = 0; rt < 2; ++rt)
            #pragma unroll
            for (int r = 0; r < 4; ++r)
                s_fin[wave * 32 + rt * 16 + q * 4 + r] = bidx[rt][r];
    }
    __syncthreads();

    // ---- indices output (coalesced)
    if (tid < 128)
        out[3 * (size_t)OUT_STRIDE + mbase + tid] = (float)s_fin[tid];

    // ---- coalesced epilogue over the 128x64 tile:
    // out0 = exact x (LDS), out1 = emb[idx], out2 = (x + q) - x.
    {
        const size_t base = (size_t)mbase * (E_DIM / 4);
        float4* o0 = (float4*)out + base;
        float4* o1 = (float4*)(out + OUT_STRIDE) + base;
        float4* o2 = (float4*)(out + 2 * (size_t)OUT_STRIDE) + base;
        #pragma unroll
        for (int i = 0; i < 8; ++i) {
            const int f   = i * 256 + tid;
            const int row = f >> 4;
            const int col = (f & 15) * 4;
            const float4 xv = *(const float4*)(&s_x[row * XPAD + col]);
            const int idx = s_fin[row];
            const float4 qv = *(const float4*)(emb + (size_t)idx * E_DIM + col);
            float4 z;
            z.x = __fsub_rn(__fadd_rn(xv.x, qv.x), xv.x);
            z.y = __fsub_rn(__fadd_rn(xv.y, qv.y), xv.y);
            z.z = __fsub_rn(__fadd_rn(xv.z, qv.z), xv.z);
            z.w = __fsub_rn(__fadd_rn(xv.w, qv.w), xv.w);
            o0[f] = xv;
            o1[f] = qv;
            o2[f] = z;
        }
    }
}

// ---------------------------------------------------------------------------
extern "C" void kernel_launch(void* const* d_in, const int* in_sizes, int n_in,
                              void* d_out, int out_size, void* d_ws, size_t ws_size,
                              hipStream_t stream) {
    const float* x   = (const float*)d_in[0];
    const float* emb = (const float*)d_in[1];
    float* out  = (float*)d_out;
    float* ebuf = (float*)d_ws;   // 64 * 5120 B = 320 KB staged codebook

    hipLaunchKernelGGL(vq_swizzle_kernel, dim3(NT_TOTAL), dim3(128), 0, stream,
                       emb, ebuf);
    hipLaunchKernelGGL(vq_fused_kernel, dim3(L_TOTAL / 128), dim3(256), 0, stream,
                       x, emb, ebuf, out);
}

// Round 7
// 121.382 us; speedup vs baseline: 1.1143x; 1.1143x over previous
//
#include <hip/hip_runtime.h>

#define L_TOTAL   32768
#define E_DIM     64
#define K_TOTAL   1024
#define NT_TOTAL  64                  // K_TOTAL / 16
#define OUT_STRIDE 2097152            // L_TOTAL * E_DIM

// staging record: per nt = 1280 words (5120 B):
//   [0,256)    kt0 hi frags (64 lanes x 16 B)
//   [256,512)  kt1 hi
//   [512,768)  kt0 lo
//   [768,1024) kt1 lo
//   [1024,1088) norms (64 f32, dup x4 over quads)
//   [1088,1280) pad
#define NT_WORDS  1280

// ws layout (bytes)
#define WS_EBUF   0u                          // 64 * 5120 = 327680 B
#define WS_PART   327680u                     // float2 [16 slice][32768 lat] = 4 MB

typedef _Float16 half_t;
typedef _Float16 half8  __attribute__((ext_vector_type(8)));
typedef float    floatx4 __attribute__((ext_vector_type(4)));

// ---------------------------------------------------------------------------
// Codebook fp32 -> staged records (f16 hi/lo fragments + norms).
// Fragment (nt,kt,lane) = e[nt*16 + (lane&15)][kt*32 + (lane>>4)*8 .. +8].
// ---------------------------------------------------------------------------
__global__ __launch_bounds__(128)
void vq_swizzle_kernel(const float* __restrict__ emb, float* __restrict__ ebuf) {
    __shared__ float s_p[128];
    __shared__ float s_n[16];
    const int nt   = blockIdx.x;
    const int t    = threadIdx.x;
    const int kt   = t >> 6;
    const int lane = t & 63;
    const int q    = lane >> 4;
    const int ln   = lane & 15;

    const float* src = emb + (size_t)(nt * 16 + ln) * E_DIM + kt * 32 + q * 8;
    float4 v0 = *(const float4*)src;
    float4 v1 = *(const float4*)(src + 4);
    float f[8] = {v0.x, v0.y, v0.z, v0.w, v1.x, v1.y, v1.z, v1.w};

    half8 h, l;
    float s = 0.f;
    #pragma unroll
    for (int j = 0; j < 8; ++j) {
        half_t hh = (half_t)f[j];
        half_t ll = (half_t)(f[j] - (float)hh);
        h[j] = hh;
        l[j] = ll;
        s = fmaf(f[j], f[j], s);
    }
    float* rec = ebuf + (size_t)nt * NT_WORDS;
    *(half8*)(rec + kt * 256 + lane * 4)       = h;   // hi
    *(half8*)(rec + 512 + kt * 256 + lane * 4) = l;   // lo

    s_p[t] = s;
    __syncthreads();
    if (t < 16) {
        float n = 0.f;
        #pragma unroll
        for (int u = 0; u < 8; ++u)
            n += s_p[(u >> 2) * 64 + (u & 3) * 16 + t];
        s_n[t] = n;
    }
    __syncthreads();
    if (t < 64) rec[1024 + t] = s_n[t & 15];
}

// ---------------------------------------------------------------------------
// Barrier-free K-sliced argmin. Grid 2048 x 256 thr. Block b: slice s=b&15
// (nt = s*4..s*4+4), group-quad gq=b>>4; wave w owns latents (gq*4+w)*64..+64
// (rt=4). 8192 independent waves, no __syncthreads in the hot path. Block's
// 4 waves share one B stream (L1 reuse); B register-pipelined 1 deep.
// Partials (best,idx) per (slice, latent) -> ws.
// ---------------------------------------------------------------------------
__global__ __launch_bounds__(256, 3)
void vq_argmin_kernel(const float* __restrict__ x,
                      const float* __restrict__ ebuf,
                      float2* __restrict__ partial) {
    const int tid   = threadIdx.x;
    const int wave  = tid >> 6;
    const int lane  = tid & 63;
    const int q     = lane >> 4;
    const int ln    = lane & 15;
    const int s     = blockIdx.x & 15;            // K slice (4 nt)
    const int group = (blockIdx.x >> 4) * 4 + wave;
    const int mbase = group * 64;
    const int nt0   = s * 4;

    // ---- issue slice's first B prefetch immediately (covered by A work)
    const float* rec0 = ebuf + (size_t)nt0 * NT_WORDS;
    half8 nb0 = *(const half8*)(rec0 + lane * 4);
    half8 nb1 = *(const half8*)(rec0 + 256 + lane * 4);
    half8 nb2 = *(const half8*)(rec0 + 512 + lane * 4);
    half8 nb3 = *(const half8*)(rec0 + 768 + lane * 4);
    float nenv = rec0[1024 + lane];

    // ---- A fragments (hi/lo) + row norms, 64 latents (rt=4)
    half8 A[4][2][2];                  // [rt][kt][hi/lo]
    floatx4 xq[4];
    #pragma unroll
    for (int rt = 0; rt < 4; ++rt) {
        const float* xr = x + (size_t)(mbase + rt * 16 + ln) * E_DIM + q * 8;
        float sn = 0.f;
        #pragma unroll
        for (int kt = 0; kt < 2; ++kt) {
            float4 v0 = *(const float4*)(xr + kt * 32);
            float4 v1 = *(const float4*)(xr + kt * 32 + 4);
            float f[8] = {v0.x, v0.y, v0.z, v0.w, v1.x, v1.y, v1.z, v1.w};
            #pragma unroll
            for (int j = 0; j < 8; ++j) {
                half_t hh = (half_t)f[j];
                half_t ll = (half_t)(f[j] - (float)hh);
                A[rt][kt][0][j] = hh;
                A[rt][kt][1][j] = ll;
                sn = fmaf(f[j], f[j], sn);
            }
        }
        sn += __shfl_xor(sn, 16, 64);
        sn += __shfl_xor(sn, 32, 64);
        #pragma unroll
        for (int r = 0; r < 4; ++r)
            xq[rt][r] = __shfl(sn, q * 4 + r, 64);
    }

    float best[4][4];
    int   bidx[4][4];
    #pragma unroll
    for (int rt = 0; rt < 4; ++rt)
        #pragma unroll
        for (int r = 0; r < 4; ++r) { best[rt][r] = 3.402823466e+38f; bidx[rt][r] = 0x7fffffff; }

    // ---- 4-nt loop, 1-deep register pipeline (cur/next)
    half8 cb0, cb1, cb2, cb3;
    float cenv;
    #pragma unroll 1
    for (int j = 0; j < 4; ++j) {
        cb0 = nb0; cb1 = nb1; cb2 = nb2; cb3 = nb3; cenv = nenv;
        if (j < 3) {
            const float* rec = ebuf + (size_t)(nt0 + j + 1) * NT_WORDS;
            nb0 = *(const half8*)(rec + lane * 4);
            nb1 = *(const half8*)(rec + 256 + lane * 4);
            nb2 = *(const half8*)(rec + 512 + lane * 4);
            nb3 = *(const half8*)(rec + 768 + lane * 4);
            nenv = rec[1024 + lane];
        }
        const int nt = nt0 + j;
        const int kg = nt * 16 + ln;
        #pragma unroll
        for (int rt = 0; rt < 4; ++rt) {
            floatx4 Ca = {0.f, 0.f, 0.f, 0.f};
            floatx4 Cb = {0.f, 0.f, 0.f, 0.f};
            Ca = __builtin_amdgcn_mfma_f32_16x16x32_f16(A[rt][0][0], cb0, Ca, 0, 0, 0);
            Ca = __builtin_amdgcn_mfma_f32_16x16x32_f16(A[rt][1][0], cb1, Ca, 0, 0, 0);
            Cb = __builtin_amdgcn_mfma_f32_16x16x32_f16(A[rt][0][1], cb0, Cb, 0, 0, 0);
            Cb = __builtin_amdgcn_mfma_f32_16x16x32_f16(A[rt][1][1], cb1, Cb, 0, 0, 0);
            Cb = __builtin_amdgcn_mfma_f32_16x16x32_f16(A[rt][0][0], cb2, Cb, 0, 0, 0);
            Cb = __builtin_amdgcn_mfma_f32_16x16x32_f16(A[rt][1][0], cb3, Cb, 0, 0, 0);
            #pragma unroll
            for (int r = 0; r < 4; ++r) {
                float dot = Ca[r] + Cb[r];
                // reference op order: (xx - 2*dot) + en, no FMA contraction
                float d = __fadd_rn(__fsub_rn(xq[rt][r], __fmul_rn(2.0f, dot)), cenv);
                if (d < best[rt][r] || (d == best[rt][r] && kg < bidx[rt][r])) {
                    best[rt][r] = d; bidx[rt][r] = kg;
                }
            }
        }
    }

    // ---- argmin across the 16 col-lanes of each quad (ties -> lower index)
    #pragma unroll
    for (int o = 1; o < 16; o <<= 1) {
        #pragma unroll
        for (int rt = 0; rt < 4; ++rt)
            #pragma unroll
            for (int r = 0; r < 4; ++r) {
                float ob = __shfl_xor(best[rt][r], o, 64);
                int   oi = __shfl_xor(bidx[rt][r], o, 64);
                if (ob < best[rt][r] || (ob == best[rt][r] && oi < bidx[rt][r])) {
                    best[rt][r] = ob; bidx[rt][r] = oi;
                }
            }
    }
    if (ln == 0) {
        #pragma unroll
        for (int rt = 0; rt < 4; ++rt)
            #pragma unroll
            for (int r = 0; r < 4; ++r)
                partial[(size_t)s * L_TOTAL + mbase + rt * 16 + q * 4 + r] =
                    make_float2(best[rt][r], __int_as_float(bidx[rt][r]));
    }
}

// ---------------------------------------------------------------------------
// Reduce 16 slice-partials per latent (lexicographic == first occurrence),
// then fully-coalesced epilogue: out0 = x, out1 = emb[idx], out2 = (x+q)-x.
// Grid 512 x 256 (64 latents / block).
// ---------------------------------------------------------------------------
__global__ __launch_bounds__(256)
void vq_epilogue_kernel(const float* __restrict__ x,
                        const float* __restrict__ emb,
                        const float2* __restrict__ partial,
                        float* __restrict__ out) {
    __shared__ int s_fin[64];
    const int tid  = threadIdx.x;
    const int base = blockIdx.x * 64;

    if (tid < 64) {
        float b = 3.402823466e+38f;
        int   i = 0x7fffffff;
        #pragma unroll
        for (int s = 0; s < 16; ++s) {
            float2 p = partial[(size_t)s * L_TOTAL + base + tid];
            int    pi = __float_as_int(p.y);
            if (p.x < b || (p.x == b && pi < i)) { b = p.x; i = pi; }
        }
        s_fin[tid] = i;
        out[3 * (size_t)OUT_STRIDE + base + tid] = (float)i;   // coalesced
    }
    __syncthreads();

    const size_t fb = (size_t)base * (E_DIM / 4);
    const float4* xg = (const float4*)x + fb;
    float4* o0 = (float4*)out + fb;
    float4* o1 = (float4*)(out + OUT_STRIDE) + fb;
    float4* o2 = (float4*)(out + 2 * (size_t)OUT_STRIDE) + fb;
    #pragma unroll
    for (int i = 0; i < 4; ++i) {
        const int f   = i * 256 + tid;           // 0..1023 float4 of the tile
        const int row = f >> 4;
        const int col = (f & 15) * 4;
        const float4 xv = xg[f];
        const int idx = s_fin[row];
        const float4 qv = *(const float4*)(emb + (size_t)idx * E_DIM + col);
        float4 z;
        z.x = __fsub_rn(__fadd_rn(xv.x, qv.x), xv.x);
        z.y = __fsub_rn(__fadd_rn(xv.y, qv.y), xv.y);
        z.z = __fsub_rn(__fadd_rn(xv.z, qv.z), xv.z);
        z.w = __fsub_rn(__fadd_rn(xv.w, qv.w), xv.w);
        o0[f] = xv;
        o1[f] = qv;
        o2[f] = z;
    }
}

// ---------------------------------------------------------------------------
extern "C" void kernel_launch(void* const* d_in, const int* in_sizes, int n_in,
                              void* d_out, int out_size, void* d_ws, size_t ws_size,
                              hipStream_t stream) {
    const float* x   = (const float*)d_in[0];
    const float* emb = (const float*)d_in[1];
    float* out = (float*)d_out;

    float*  ebuf = (float*)((char*)d_ws + WS_EBUF);
    float2* part = (float2*)((char*)d_ws + WS_PART);

    hipLaunchKernelGGL(vq_swizzle_kernel, dim3(NT_TOTAL), dim3(128), 0, stream,
                       emb, ebuf);
    hipLaunchKernelGGL(vq_argmin_kernel, dim3(2048), dim3(256), 0, stream,
                       x, ebuf, part);
    hipLaunchKernelGGL(vq_epilogue_kernel, dim3(512), dim3(256), 0, stream,
                       x, emb, part, out);
}

// Round 8
// 87.934 us; speedup vs baseline: 1.5381x; 1.3804x over previous
//
#include <hip/hip_runtime.h>

#define L_TOTAL   32768
#define E_DIM     64
#define K_TOTAL   1024
#define NT_TOTAL  64                  // K_TOTAL / 16
#define OUT_STRIDE 2097152            // L_TOTAL * E_DIM
#define XPAD      68                  // fp32 x-tile LDS pitch (words)

// staging record: per nt = 1280 words (5120 B):
//   [0,256)    kt0 hi frags (64 lanes x 16 B)
//   [256,512)  kt1 hi
//   [512,768)  kt0 lo
//   [768,1024) kt1 lo
//   [1024,1088) norms (64 f32, dup x4 over quads)
//   [1088,1280) pad
#define NT_WORDS  1280

typedef _Float16 half_t;
typedef _Float16 half8  __attribute__((ext_vector_type(8)));
typedef float    floatx4 __attribute__((ext_vector_type(4)));

// ---------------------------------------------------------------------------
// Codebook fp32 -> staged records (f16 hi/lo fragments + norms).
// Fragment (nt,kt,lane) = e[nt*16 + (lane&15)][kt*32 + (lane>>4)*8 .. +8].
// ---------------------------------------------------------------------------
__global__ __launch_bounds__(128)
void vq_swizzle_kernel(const float* __restrict__ emb, float* __restrict__ ebuf) {
    __shared__ float s_p[128];
    __shared__ float s_n[16];
    const int nt   = blockIdx.x;
    const int t    = threadIdx.x;
    const int kt   = t >> 6;
    const int lane = t & 63;
    const int q    = lane >> 4;
    const int ln   = lane & 15;

    const float* src = emb + (size_t)(nt * 16 + ln) * E_DIM + kt * 32 + q * 8;
    float4 v0 = *(const float4*)src;
    float4 v1 = *(const float4*)(src + 4);
    float f[8] = {v0.x, v0.y, v0.z, v0.w, v1.x, v1.y, v1.z, v1.w};

    half8 h, l;
    float s = 0.f;
    #pragma unroll
    for (int j = 0; j < 8; ++j) {
        half_t hh = (half_t)f[j];
        half_t ll = (half_t)(f[j] - (float)hh);
        h[j] = hh;
        l[j] = ll;
        s = fmaf(f[j], f[j], s);
    }
    float* rec = ebuf + (size_t)nt * NT_WORDS;
    *(half8*)(rec + kt * 256 + lane * 4)       = h;   // hi
    *(half8*)(rec + 512 + kt * 256 + lane * 4) = l;   // lo

    s_p[t] = s;
    __syncthreads();
    if (t < 16) {
        float n = 0.f;
        #pragma unroll
        for (int u = 0; u < 8; ++u)
            n += s_p[(u >> 2) * 64 + (u & 3) * 16 + t];
        s_n[t] = n;
    }
    __syncthreads();
    if (t < 64) rec[1024 + t] = s_n[t & 15];
}

// ---------------------------------------------------------------------------
// Fused distances + argmin + epilogue. SPILL-FREE by design (~110 VGPRs).
// Grid 1024 x 256: block = 4 waves over the SAME 32 latents (rt=2/wave);
// wave ks scans K-quarter [ks*256, +256) = 16 nt, rotated per block.
// B: explicit two-buffer register rotation (one load always in flight).
// Lexicographic (dist,index) argmin == numpy first-occurrence, order-indep.
// ---------------------------------------------------------------------------
__global__ __launch_bounds__(256, 4)
void vq_fused_kernel(const float* __restrict__ x,
                     const float* __restrict__ emb,
                     const float* __restrict__ ebuf,
                     float* __restrict__ out) {
    __shared__ float s_x[32 * XPAD];   // 8704 B fp32 x tile
    __shared__ float s_best[4][32];
    __shared__ int   s_bidx[4][32];
    __shared__ int   s_fin[32];

    const int tid   = threadIdx.x;
    const int ks    = tid >> 6;        // K-split wave 0..3
    const int lane  = tid & 63;
    const int q     = lane >> 4;
    const int ln    = lane & 15;
    const int mbase = blockIdx.x * 32;
    const int rot   = blockIdx.x & 15;
    const int nt0   = ks * 16;

    // ---- stage x tile: coalesced float4 -> padded LDS (2 per thread)
    {
        const float4* xg = (const float4*)(x + (size_t)mbase * E_DIM);
        #pragma unroll
        for (int i = 0; i < 2; ++i) {
            const int f   = i * 256 + tid;       // 0..511 float4 of tile
            const int row = f >> 4;
            const int col = (f & 15) * 4;
            *(float4*)(&s_x[row * XPAD + col]) = xg[f];
        }
    }
    __syncthreads();

    // ---- A fragments (hi/lo) + row norms for the block's 32 latents
    half8 A[2][2][2];                  // [rt][kt][hi/lo]  = 32 VGPRs
    floatx4 xq[2];
    #pragma unroll
    for (int rt = 0; rt < 2; ++rt) {
        const float* xr = &s_x[(rt * 16 + ln) * XPAD + q * 8];
        float sn = 0.f;
        #pragma unroll
        for (int kt = 0; kt < 2; ++kt) {
            float4 v0 = *(const float4*)(xr + kt * 32);
            float4 v1 = *(const float4*)(xr + kt * 32 + 4);
            float f[8] = {v0.x, v0.y, v0.z, v0.w, v1.x, v1.y, v1.z, v1.w};
            #pragma unroll
            for (int j = 0; j < 8; ++j) {
                half_t hh = (half_t)f[j];
                half_t ll = (half_t)(f[j] - (float)hh);
                A[rt][kt][0][j] = hh;
                A[rt][kt][1][j] = ll;
                sn = fmaf(f[j], f[j], sn);
            }
        }
        sn += __shfl_xor(sn, 16, 64);
        sn += __shfl_xor(sn, 32, 64);
        #pragma unroll
        for (int r = 0; r < 4; ++r)
            xq[rt][r] = __shfl(sn, q * 4 + r, 64);
    }

    float best[2][4];
    int   bidx[2][4];
    #pragma unroll
    for (int rt = 0; rt < 2; ++rt)
        #pragma unroll
        for (int r = 0; r < 4; ++r) { best[rt][r] = 3.402823466e+38f; bidx[rt][r] = 0x7fffffff; }

    // ---- K loop: 16 nt, two-buffer register pipeline (no spill, 1 in flight)
    half8 a0, a1, a2, a3; float ae;    // buffer A
    half8 b0, b1, b2, b3; float be;    // buffer B
    int nt_a, nt_b;
    {
        nt_a = nt0 + rot;              // (rot in [0,16) -> stays in quarter? no:
        nt_a = nt0 + (rot & 15);       //  rot<16, nt0+rot may exceed quarter; wrap:
        nt_a = nt0 + ((0 + rot) & 15);
        const float* rec = ebuf + (size_t)nt_a * NT_WORDS;
        a0 = *(const half8*)(rec + lane * 4);
        a1 = *(const half8*)(rec + 256 + lane * 4);
        a2 = *(const half8*)(rec + 512 + lane * 4);
        a3 = *(const half8*)(rec + 768 + lane * 4);
        ae = rec[1024 + lane];
    }

    #pragma unroll 1
    for (int j = 0; j < 16; j += 2) {
        // prefetch j+1 into buffer B
        nt_b = nt0 + ((j + 1 + rot) & 15);
        {
            const float* rec = ebuf + (size_t)nt_b * NT_WORDS;
            b0 = *(const half8*)(rec + lane * 4);
            b1 = *(const half8*)(rec + 256 + lane * 4);
            b2 = *(const half8*)(rec + 512 + lane * 4);
            b3 = *(const half8*)(rec + 768 + lane * 4);
            be = rec[1024 + lane];
        }
        // compute buffer A (nt_a)
        {
            const int kg = nt_a * 16 + ln;
            #pragma unroll
            for (int rt = 0; rt < 2; ++rt) {
                floatx4 Ca = {0.f, 0.f, 0.f, 0.f};
                floatx4 Cb = {0.f, 0.f, 0.f, 0.f};
                Ca = __builtin_amdgcn_mfma_f32_16x16x32_f16(A[rt][0][0], a0, Ca, 0, 0, 0);
                Ca = __builtin_amdgcn_mfma_f32_16x16x32_f16(A[rt][1][0], a1, Ca, 0, 0, 0);
                Cb = __builtin_amdgcn_mfma_f32_16x16x32_f16(A[rt][0][1], a0, Cb, 0, 0, 0);
                Cb = __builtin_amdgcn_mfma_f32_16x16x32_f16(A[rt][1][1], a1, Cb, 0, 0, 0);
                Cb = __builtin_amdgcn_mfma_f32_16x16x32_f16(A[rt][0][0], a2, Cb, 0, 0, 0);
                Cb = __builtin_amdgcn_mfma_f32_16x16x32_f16(A[rt][1][0], a3, Cb, 0, 0, 0);
                #pragma unroll
                for (int r = 0; r < 4; ++r) {
                    float dot = Ca[r] + Cb[r];
                    float d = __fadd_rn(__fsub_rn(xq[rt][r], __fmul_rn(2.0f, dot)), ae);
                    if (d < best[rt][r] || (d == best[rt][r] && kg < bidx[rt][r])) {
                        best[rt][r] = d; bidx[rt][r] = kg;
                    }
                }
            }
        }
        // prefetch j+2 into buffer A
        if (j + 2 < 16) {
            nt_a = nt0 + ((j + 2 + rot) & 15);
            const float* rec = ebuf + (size_t)nt_a * NT_WORDS;
            a0 = *(const half8*)(rec + lane * 4);
            a1 = *(const half8*)(rec + 256 + lane * 4);
            a2 = *(const half8*)(rec + 512 + lane * 4);
            a3 = *(const half8*)(rec + 768 + lane * 4);
            ae = rec[1024 + lane];
        }
        // compute buffer B (nt_b)
        {
            const int kg = nt_b * 16 + ln;
            #pragma unroll
            for (int rt = 0; rt < 2; ++rt) {
                floatx4 Ca = {0.f, 0.f, 0.f, 0.f};
                floatx4 Cb = {0.f, 0.f, 0.f, 0.f};
                Ca = __builtin_amdgcn_mfma_f32_16x16x32_f16(A[rt][0][0], b0, Ca, 0, 0, 0);
                Ca = __builtin_amdgcn_mfma_f32_16x16x32_f16(A[rt][1][0], b1, Ca, 0, 0, 0);
                Cb = __builtin_amdgcn_mfma_f32_16x16x32_f16(A[rt][0][1], b0, Cb, 0, 0, 0);
                Cb = __builtin_amdgcn_mfma_f32_16x16x32_f16(A[rt][1][1], b1, Cb, 0, 0, 0);
                Cb = __builtin_amdgcn_mfma_f32_16x16x32_f16(A[rt][0][0], b2, Cb, 0, 0, 0);
                Cb = __builtin_amdgcn_mfma_f32_16x16x32_f16(A[rt][1][0], b3, Cb, 0, 0, 0);
                #pragma unroll
                for (int r = 0; r < 4; ++r) {
                    float dot = Ca[r] + Cb[r];
                    float d = __fadd_rn(__fsub_rn(xq[rt][r], __fmul_rn(2.0f, dot)), be);
                    if (d < best[rt][r] || (d == best[rt][r] && kg < bidx[rt][r])) {
                        best[rt][r] = d; bidx[rt][r] = kg;
                    }
                }
            }
        }
    }

    // ---- argmin across the 16 col-lanes of each quad (ties -> lower index)
    #pragma unroll
    for (int o = 1; o < 16; o <<= 1) {
        #pragma unroll
        for (int rt = 0; rt < 2; ++rt)
            #pragma unroll
            for (int r = 0; r < 4; ++r) {
                float ob = __shfl_xor(best[rt][r], o, 64);
                int   oi = __shfl_xor(bidx[rt][r], o, 64);
                if (ob < best[rt][r] || (ob == best[rt][r] && oi < bidx[rt][r])) {
                    best[rt][r] = ob; bidx[rt][r] = oi;
                }
            }
    }
    if (ln == 0) {
        #pragma unroll
        for (int rt = 0; rt < 2; ++rt)
            #pragma unroll
            for (int r = 0; r < 4; ++r) {
                s_best[ks][rt * 16 + q * 4 + r] = best[rt][r];
                s_bidx[ks][rt * 16 + q * 4 + r] = bidx[rt][r];
            }
    }
    __syncthreads();

    // ---- merge the 4 K-splits (lexicographic == first-occurrence)
    if (tid < 32) {
        float b = 3.402823466e+38f;
        int   i = 0x7fffffff;
        #pragma unroll
        for (int s = 0; s < 4; ++s) {
            float pb = s_best[s][tid];
            int   pi = s_bidx[s][tid];
            if (pb < b || (pb == b && pi < i)) { b = pb; i = pi; }
        }
        s_fin[tid] = i;
        out[3 * (size_t)OUT_STRIDE + mbase + tid] = (float)i;   // coalesced
    }
    __syncthreads();

    // ---- coalesced epilogue over the 32x64 tile:
    // out0 = exact x (LDS), out1 = emb[idx], out2 = (x + q) - x.
    {
        const size_t fb = (size_t)mbase * (E_DIM / 4);
        float4* o0 = (float4*)out + fb;
        float4* o1 = (float4*)(out + OUT_STRIDE) + fb;
        float4* o2 = (float4*)(out + 2 * (size_t)OUT_STRIDE) + fb;
        #pragma unroll
        for (int i = 0; i < 2; ++i) {
            const int f   = i * 256 + tid;       // 0..511
            const int row = f >> 4;
            const int col = (f & 15) * 4;
            const float4 xv = *(const float4*)(&s_x[row * XPAD + col]);
            const int idx = s_fin[row];
            const float4 qv = *(const float4*)(emb + (size_t)idx * E_DIM + col);
            float4 z;
            z.x = __fsub_rn(__fadd_rn(xv.x, qv.x), xv.x);
            z.y = __fsub_rn(__fadd_rn(xv.y, qv.y), xv.y);
            z.z = __fsub_rn(__fadd_rn(xv.z, qv.z), xv.z);
            z.w = __fsub_rn(__fadd_rn(xv.w, qv.w), xv.w);
            o0[f] = xv;
            o1[f] = qv;
            o2[f] = z;
        }
    }
}

// ---------------------------------------------------------------------------
extern "C" void kernel_launch(void* const* d_in, const int* in_sizes, int n_in,
                              void* d_out, int out_size, void* d_ws, size_t ws_size,
                              hipStream_t stream) {
    const float* x   = (const float*)d_in[0];
    const float* emb = (const float*)d_in[1];
    float* out  = (float*)d_out;
    float* ebuf = (float*)d_ws;   // 64 * 5120 B = 320 KB staged codebook

    hipLaunchKernelGGL(vq_swizzle_kernel, dim3(NT_TOTAL), dim3(128), 0, stream,
                       emb, ebuf);
    hipLaunchKernelGGL(vq_fused_kernel, dim3(L_TOTAL / 32), dim3(256), 0, stream,
                       x, emb, ebuf, out);
}